// Round 5
// baseline (129.233 us; speedup 1.0000x reference)
//
#include <hip/hip_runtime.h>

#define N_NODES 50000
#define E_EDGES 625000
#define D 128

#define NB_M 391                               // ceil(N/128) gemm blocks
#define PREP_BLOCKS ((E_EDGES + 255) / 256)    // 2442 prep blocks

typedef __attribute__((ext_vector_type(8)))  short  short8;
typedef __attribute__((ext_vector_type(16))) float  floatx16;

static __device__ inline unsigned short f2bf(float f) {
    union { float f; unsigned u; } v; v.f = f;
    unsigned r = v.u + 0x7FFFu + ((v.u >> 16) & 1u);   // RNE
    return (unsigned short)(r >> 16);
}
static __device__ inline float bflo(unsigned p) { return __uint_as_float(p << 16); }
static __device__ inline float bfhi(unsigned p) { return __uint_as_float(p & 0xFFFF0000u); }

// ---------------------------------------------------------------------------
// Kernel 1 (fused): one grid, two independent block families.
//  blocks [0, NB_M):        GEMM  [Z1b | Y] = bf16(feat @ [W1 | W2])
//    - each block converts W f32->bf16 straight into its LDS (W is 128 KB,
//      L2-resident after first touch)
//  blocks [NB_M, NB_M+2442): prep (rowptr + meta), runs CONCURRENTLY with
//    the GEMM blocks since neither family depends on the other.
// ---------------------------------------------------------------------------
__global__ __launch_bounds__(256, 2) void fused_prep_gemm(
        const float* __restrict__ feat,
        const float* __restrict__ W,
        const int*   __restrict__ dst,
        const int*   __restrict__ src,
        const float* __restrict__ affine,
        int*            __restrict__ rowptr,
        uint2*          __restrict__ meta,
        unsigned short* __restrict__ Z1b,
        unsigned short* __restrict__ Y) {
    __shared__ short8 Bls[4096];   // 64 KB: both halves of W, bf16

    int tid = threadIdx.x;
    int bid = blockIdx.x;

    if (bid >= NB_M) {
        // ---- prep path: rowptr + meta (edge-parallel, streaming) ----
        int t = (bid - NB_M) * 256 + tid;
        if (t < E_EDGES) {
            int d1 = dst[t];
            int d0 = (t == 0) ? -1 : dst[t - 1];
            for (int n = d0 + 1; n <= d1; ++n) rowptr[n] = t;
            if (t == E_EDGES - 1)
                for (int n = d1 + 1; n <= N_NODES; ++n) rowptr[n] = E_EDGES;
            uint2 m;
            m.x = (unsigned)src[t];
            m.y = __float_as_uint(affine[t]);
            meta[t] = m;
        }
        return;
    }

    // ---- gemm path ----
    // Convert W directly into LDS. Slot s = h*2048 + c*128 + n holds
    // W[h*128+c*8+j][n], j=0..7. Reads are coalesced across n.
    #pragma unroll
    for (int i = 0; i < 16; ++i) {
        int s = tid + i * 256;
        int n = s & 127;
        int c = (s >> 7) & 15;
        int h = s >> 11;
        int krow = h * 128 + c * 8;
        short8 v;
        #pragma unroll
        for (int j = 0; j < 8; ++j)
            v[j] = (short)f2bf(W[(size_t)(krow + j) * D + n]);
        Bls[s] = v;
    }

    int wave = tid >> 6;
    int lane = tid & 63;
    int m = lane & 31;
    int g = lane >> 5;
    int row0   = bid * 128 + wave * 32;
    int row_a  = row0 + m;
    int rclamp = row_a < N_NODES ? row_a : 0;

    short8 fa[8];
    const float* ap = feat + (size_t)rclamp * D + g * 8;
    #pragma unroll
    for (int ks = 0; ks < 8; ++ks) {
        float4 u = *(const float4*)(ap + ks * 16);
        float4 v = *(const float4*)(ap + ks * 16 + 4);
        short8 a;
        a[0] = (short)f2bf(u.x); a[1] = (short)f2bf(u.y);
        a[2] = (short)f2bf(u.z); a[3] = (short)f2bf(u.w);
        a[4] = (short)f2bf(v.x); a[5] = (short)f2bf(v.y);
        a[6] = (short)f2bf(v.z); a[7] = (short)f2bf(v.w);
        fa[ks] = a;
    }
    __syncthreads();

    #pragma unroll
    for (int h = 0; h < 2; ++h) {
        unsigned short* dstbuf = h ? Y : Z1b;
        #pragma unroll
        for (int t4 = 0; t4 < 4; ++t4) {
            int n = t4 * 32 + m;
            floatx16 acc = {0,0,0,0, 0,0,0,0, 0,0,0,0, 0,0,0,0};
            #pragma unroll
            for (int ks = 0; ks < 8; ++ks) {
                short8 bb = Bls[h * 2048 + (ks * 2 + g) * 128 + n];
                acc = __builtin_amdgcn_mfma_f32_32x32x16_bf16(fa[ks], bb, acc, 0, 0, 0);
            }
            // D layout: col = lane&31, row = (reg&3) + 8*(reg>>2) + 4*g
            #pragma unroll
            for (int r = 0; r < 16; ++r) {
                int row = row0 + (r & 3) + 8 * (r >> 2) + 4 * g;
                if (row < N_NODES) dstbuf[(size_t)row * D + n] = f2bf(acc[r]);
            }
        }
    }
}

// ---------------------------------------------------------------------------
// Kernel 2: out[n,:] = bf2f(Z1b[n,:]) + bias + sum_e affine[e] * Y[src[e],:]
// One wave per node; quarter g owns edge slot, lane owns 8 features (uint4).
// 16 edges in flight per round. Tail slots are now PREDICATED (i<hi is
// uniform within each 16-lane group): masked slots issue NO meta/Y loads,
// eliminating the ~29% wasted gather traffic the clamped version paid.
// Dropped terms were exact +0.0 contributions -> numerically identical.
// ---------------------------------------------------------------------------
__global__ __launch_bounds__(256) void agg_add(const unsigned short* __restrict__ Y,
                                               const unsigned short* __restrict__ Z1b,
                                               const uint2* __restrict__ meta,
                                               const int* __restrict__ rowptr,
                                               const float* __restrict__ bias,
                                               float* __restrict__ out) {
    int wave = threadIdx.x >> 6;
    int lane = threadIdx.x & 63;
    int n = blockIdx.x * 4 + wave;
    if (n >= N_NODES) return;
    int lo = rowptr[n], hi = rowptr[n + 1];
    int g  = lane >> 4;
    int jj = (lane & 15) << 3;
    const unsigned short* Yj = Y + jj;

    // Epilogue operands issued early — overlap with the gather chain below.
    uint4  z  = *(const uint4*)(Z1b + (size_t)n * D + jj);
    float4 b0 = *(const float4*)(bias + jj);
    float4 b1 = *(const float4*)(bias + jj + 4);

    float acc[8] = {0,0,0,0,0,0,0,0};

    for (int e0 = lo; e0 < hi; e0 += 16) {
        uint2 md[4];
        bool  act[4];
        #pragma unroll
        for (int u = 0; u < 4; ++u) {
            int i = e0 + u * 4 + g;
            act[u] = i < hi;
            if (act[u]) md[u] = meta[i];
        }
        float w[4];
        uint4 p[4];
        #pragma unroll
        for (int u = 0; u < 4; ++u) {
            if (act[u]) {
                w[u] = __uint_as_float(md[u].y);
                p[u] = *(const uint4*)(Yj + (size_t)md[u].x * D);
            }
        }
        #pragma unroll
        for (int u = 0; u < 4; ++u) {
            if (act[u]) {
                acc[0] += bflo(p[u].x) * w[u];  acc[1] += bfhi(p[u].x) * w[u];
                acc[2] += bflo(p[u].y) * w[u];  acc[3] += bfhi(p[u].y) * w[u];
                acc[4] += bflo(p[u].z) * w[u];  acc[5] += bfhi(p[u].z) * w[u];
                acc[6] += bflo(p[u].w) * w[u];  acc[7] += bfhi(p[u].w) * w[u];
            }
        }
    }

    #pragma unroll
    for (int r = 0; r < 8; ++r) {
        acc[r] += __shfl_xor(acc[r], 16);
        acc[r] += __shfl_xor(acc[r], 32);
    }

    if (g == 0) {
        float* op = out + (size_t)n * D + jj;
        float4 o0, o1;
        o0.x = bflo(z.x) + b0.x + acc[0];  o0.y = bfhi(z.x) + b0.y + acc[1];
        o0.z = bflo(z.y) + b0.z + acc[2];  o0.w = bfhi(z.y) + b0.w + acc[3];
        o1.x = bflo(z.z) + b1.x + acc[4];  o1.y = bfhi(z.z) + b1.y + acc[5];
        o1.z = bflo(z.w) + b1.z + acc[6];  o1.w = bfhi(z.w) + b1.w + acc[7];
        *(float4*)op       = o0;
        *(float4*)(op + 4) = o1;
    }
}

// ---------------------------------------------------------------------------
extern "C" void kernel_launch(void* const* d_in, const int* in_sizes, int n_in,
                              void* d_out, int out_size, void* d_ws, size_t ws_size,
                              hipStream_t stream) {
    const float* feat   = (const float*)d_in[0];
    const float* affine = (const float*)d_in[1];
    const int*   src    = (const int*)  d_in[2];
    const int*   dst    = (const int*)  d_in[3];
    const float* W      = (const float*)d_in[4];
    const float* bias   = (const float*)d_in[5];
    float*       out    = (float*)d_out;

    // ws: rowptr @64K; meta 5MB @266240; Y 12.8MB @5267456; Z1b @18067456.
    int*            rowptr = (int*)((char*)d_ws + 65536);
    uint2*          meta   = (uint2*)((char*)d_ws + 266240);
    unsigned short* Y      = (unsigned short*)((char*)d_ws + 5267456);
    unsigned short* Z1b    = (unsigned short*)((char*)d_ws + 18067456);

    fused_prep_gemm<<<NB_M + PREP_BLOCKS, 256, 0, stream>>>(
        feat, W, dst, src, affine, rowptr, meta, Z1b, Y);
    agg_add<<<(N_NODES + 3) / 4, 256, 0, stream>>>(Y, Z1b, meta, rowptr, bias, out);
}

// Round 6
// 127.649 us; speedup vs baseline: 1.0124x; 1.0124x over previous
//
#include <hip/hip_runtime.h>

#define N_NODES 50000
#define E_EDGES 625000
#define D 128

#define NB_M 391                               // ceil(N/128) gemm blocks (512 thr)
#define PREP_BLOCKS ((E_EDGES + 511) / 512)    // 1221 prep blocks (512 thr)

typedef __attribute__((ext_vector_type(8)))  short  short8;
typedef __attribute__((ext_vector_type(16))) float  floatx16;

static __device__ inline unsigned short f2bf(float f) {
    union { float f; unsigned u; } v; v.f = f;
    unsigned r = v.u + 0x7FFFu + ((v.u >> 16) & 1u);   // RNE
    return (unsigned short)(r >> 16);
}
static __device__ inline float bflo(unsigned p) { return __uint_as_float(p << 16); }
static __device__ inline float bfhi(unsigned p) { return __uint_as_float(p & 0xFFFF0000u); }

// ---------------------------------------------------------------------------
// Kernel 1 (fused): one grid, two independent block families, 512 threads.
//  blocks [0, NB_M):   GEMM  [Z1b | Y] = bf16(feat @ [W1 | W2])
//    8 waves = 4 row-groups x 2 W-halves. Same 128-row tile / 64 KB LDS as
//    before, but W-conversion + stores per thread HALVE and occupancy
//    doubles (2 blocks/CU -> 16 waves/CU) to hide the conv/store latency.
//  blocks [NB_M, ...): prep (rowptr + meta), concurrent with GEMM blocks.
// ---------------------------------------------------------------------------
__global__ __launch_bounds__(512, 4) void fused_prep_gemm(
        const float* __restrict__ feat,
        const float* __restrict__ W,
        const int*   __restrict__ dst,
        const int*   __restrict__ src,
        const float* __restrict__ affine,
        int*            __restrict__ rowptr,
        uint2*          __restrict__ meta,
        unsigned short* __restrict__ Z1b,
        unsigned short* __restrict__ Y) {
    __shared__ short8 Bls[4096];   // 64 KB: both halves of W, bf16

    int tid = threadIdx.x;
    int bid = blockIdx.x;

    if (bid >= NB_M) {
        // ---- prep path: rowptr + meta (edge-parallel, streaming) ----
        int t = (bid - NB_M) * 512 + tid;
        if (t < E_EDGES) {
            int d1 = dst[t];
            int d0 = (t == 0) ? -1 : dst[t - 1];
            for (int n = d0 + 1; n <= d1; ++n) rowptr[n] = t;
            if (t == E_EDGES - 1)
                for (int n = d1 + 1; n <= N_NODES; ++n) rowptr[n] = E_EDGES;
            uint2 m;
            m.x = (unsigned)src[t];
            m.y = __float_as_uint(affine[t]);
            meta[t] = m;
        }
        return;
    }

    // ---- gemm path ----
    // Convert W directly into LDS (512 threads x 8 slots each).
    // Slot s = h*2048 + c*128 + n holds W[h*128+c*8+j][n], j=0..7.
    #pragma unroll
    for (int i = 0; i < 8; ++i) {
        int s = tid + i * 512;
        int n = s & 127;
        int c = (s >> 7) & 15;
        int h = s >> 11;
        int krow = h * 128 + c * 8;
        short8 v;
        #pragma unroll
        for (int j = 0; j < 8; ++j)
            v[j] = (short)f2bf(W[(size_t)(krow + j) * D + n]);
        Bls[s] = v;
    }

    int wave = tid >> 6;
    int lane = tid & 63;
    int h    = wave >> 2;        // W half this wave computes
    int wq   = wave & 3;         // row-group
    int m = lane & 31;
    int g = lane >> 5;
    int row0   = bid * 128 + wq * 32;
    int row_a  = row0 + m;
    int rclamp = row_a < N_NODES ? row_a : 0;

    short8 fa[8];
    const float* ap = feat + (size_t)rclamp * D + g * 8;
    #pragma unroll
    for (int ks = 0; ks < 8; ++ks) {
        float4 u = *(const float4*)(ap + ks * 16);
        float4 v = *(const float4*)(ap + ks * 16 + 4);
        short8 a;
        a[0] = (short)f2bf(u.x); a[1] = (short)f2bf(u.y);
        a[2] = (short)f2bf(u.z); a[3] = (short)f2bf(u.w);
        a[4] = (short)f2bf(v.x); a[5] = (short)f2bf(v.y);
        a[6] = (short)f2bf(v.z); a[7] = (short)f2bf(v.w);
        fa[ks] = a;
    }
    __syncthreads();

    unsigned short* dstbuf = h ? Y : Z1b;

    #pragma unroll
    for (int t4 = 0; t4 < 4; ++t4) {
        int n = t4 * 32 + m;
        floatx16 acc = {0,0,0,0, 0,0,0,0, 0,0,0,0, 0,0,0,0};
        #pragma unroll
        for (int ks = 0; ks < 8; ++ks) {
            short8 bb = Bls[h * 2048 + (ks * 2 + g) * 128 + n];
            acc = __builtin_amdgcn_mfma_f32_32x32x16_bf16(fa[ks], bb, acc, 0, 0, 0);
        }
        // D layout: col = lane&31, row = (reg&3) + 8*(reg>>2) + 4*g
        #pragma unroll
        for (int r = 0; r < 16; ++r) {
            int row = row0 + (r & 3) + 8 * (r >> 2) + 4 * g;
            if (row < N_NODES) dstbuf[(size_t)row * D + n] = f2bf(acc[r]);
        }
    }
}

// ---------------------------------------------------------------------------
// Kernel 2: out[n,:] = bf2f(Z1b[n,:]) + bias + sum_e affine[e] * Y[src[e],:]
// One wave per node; quarter g owns edge slot, lane owns 8 features (uint4).
// 16 edges in flight per round, CLAMPED always-issued loads (R4 form —
// idle slots all hit the same meta[lo] row -> coalesced L1 hit, ~free;
// predicating them (R5) cost +5us in exec-mask overhead / lost pipelining).
// ---------------------------------------------------------------------------
__global__ __launch_bounds__(256) void agg_add(const unsigned short* __restrict__ Y,
                                               const unsigned short* __restrict__ Z1b,
                                               const uint2* __restrict__ meta,
                                               const int* __restrict__ rowptr,
                                               const float* __restrict__ bias,
                                               float* __restrict__ out) {
    int wave = threadIdx.x >> 6;
    int lane = threadIdx.x & 63;
    int n = blockIdx.x * 4 + wave;
    if (n >= N_NODES) return;
    int lo = rowptr[n], hi = rowptr[n + 1];
    int g  = lane >> 4;
    int jj = (lane & 15) << 3;
    const unsigned short* Yj = Y + jj;

    // Epilogue operands issued early — overlap with the gather chain below.
    uint4  z  = *(const uint4*)(Z1b + (size_t)n * D + jj);
    float4 b0 = *(const float4*)(bias + jj);
    float4 b1 = *(const float4*)(bias + jj + 4);

    float acc[8] = {0,0,0,0,0,0,0,0};

    for (int e0 = lo; e0 < hi; e0 += 16) {
        uint2 md[4];
        #pragma unroll
        for (int u = 0; u < 4; ++u) {
            int i = e0 + u * 4 + g;
            md[u] = meta[i < hi ? i : lo];
        }
        float w[4];
        uint4 p[4];
        #pragma unroll
        for (int u = 0; u < 4; ++u) {
            int i = e0 + u * 4 + g;
            w[u] = (i < hi) ? __uint_as_float(md[u].y) : 0.f;
            p[u] = *(const uint4*)(Yj + (size_t)md[u].x * D);
        }
        #pragma unroll
        for (int u = 0; u < 4; ++u) {
            acc[0] += bflo(p[u].x) * w[u];  acc[1] += bfhi(p[u].x) * w[u];
            acc[2] += bflo(p[u].y) * w[u];  acc[3] += bfhi(p[u].y) * w[u];
            acc[4] += bflo(p[u].z) * w[u];  acc[5] += bfhi(p[u].z) * w[u];
            acc[6] += bflo(p[u].w) * w[u];  acc[7] += bfhi(p[u].w) * w[u];
        }
    }

    #pragma unroll
    for (int r = 0; r < 8; ++r) {
        acc[r] += __shfl_xor(acc[r], 16);
        acc[r] += __shfl_xor(acc[r], 32);
    }

    if (g == 0) {
        float* op = out + (size_t)n * D + jj;
        float4 o0, o1;
        o0.x = bflo(z.x) + b0.x + acc[0];  o0.y = bfhi(z.x) + b0.y + acc[1];
        o0.z = bflo(z.y) + b0.z + acc[2];  o0.w = bfhi(z.y) + b0.w + acc[3];
        o1.x = bflo(z.z) + b1.x + acc[4];  o1.y = bfhi(z.z) + b1.y + acc[5];
        o1.z = bflo(z.w) + b1.z + acc[6];  o1.w = bfhi(z.w) + b1.w + acc[7];
        *(float4*)op       = o0;
        *(float4*)(op + 4) = o1;
    }
}

// ---------------------------------------------------------------------------
extern "C" void kernel_launch(void* const* d_in, const int* in_sizes, int n_in,
                              void* d_out, int out_size, void* d_ws, size_t ws_size,
                              hipStream_t stream) {
    const float* feat   = (const float*)d_in[0];
    const float* affine = (const float*)d_in[1];
    const int*   src    = (const int*)  d_in[2];
    const int*   dst    = (const int*)  d_in[3];
    const float* W      = (const float*)d_in[4];
    const float* bias   = (const float*)d_in[5];
    float*       out    = (float*)d_out;

    // ws: rowptr @64K; meta 5MB @266240; Y 12.8MB @5267456; Z1b @18067456.
    int*            rowptr = (int*)((char*)d_ws + 65536);
    uint2*          meta   = (uint2*)((char*)d_ws + 266240);
    unsigned short* Y      = (unsigned short*)((char*)d_ws + 5267456);
    unsigned short* Z1b    = (unsigned short*)((char*)d_ws + 18067456);

    fused_prep_gemm<<<NB_M + PREP_BLOCKS, 512, 0, stream>>>(
        feat, W, dst, src, affine, rowptr, meta, Z1b, Y);
    agg_add<<<(N_NODES + 3) / 4, 256, 0, stream>>>(Y, Z1b, meta, rowptr, bias, out);
}

// Round 7
// 123.372 us; speedup vs baseline: 1.0475x; 1.0347x over previous
//
#include <hip/hip_runtime.h>
#include <hip/hip_bf16.h>

#define N_NODES 50000
#define E_EDGES 625000
#define D 128

#define NB_M 391                               // ceil(N/128) gemm blocks
#define PREP_BLOCKS ((E_EDGES + 255) / 256)    // 2442 prep blocks

typedef __attribute__((ext_vector_type(8)))  short  short8;
typedef __attribute__((ext_vector_type(16))) float  floatx16;

// Native RNE f32->bf16 via hardware cvt (v_cvt_pk_bf16_f32 on gfx950).
// Numerically identical to the previous manual RNE bit-twiddle, ~4x fewer
// VALU ops (per learn_hip m240: compiler's scalar-cast path is optimal).
static __device__ inline unsigned short f2bf(float f) {
    __hip_bfloat16 h = __float2bfloat16(f);
    unsigned short u;
    __builtin_memcpy(&u, &h, 2);
    return u;
}
static __device__ inline float bflo(unsigned p) { return __uint_as_float(p << 16); }
static __device__ inline float bfhi(unsigned p) { return __uint_as_float(p & 0xFFFF0000u); }

// ---------------------------------------------------------------------------
// Kernel 1 (fused): one grid, two independent block families (R4 structure —
// best measured; R5 predication and R6 512-thr variants both regressed).
//  blocks [0, NB_M):   GEMM  [Z1b | Y] = bf16(feat @ [W1 | W2])
//    each block converts W f32->bf16 straight into its LDS (W is 128 KB,
//    L2-resident after first touch)
//  blocks [NB_M, ...): prep (rowptr + meta), concurrent with GEMM blocks.
// ---------------------------------------------------------------------------
__global__ __launch_bounds__(256, 2) void fused_prep_gemm(
        const float* __restrict__ feat,
        const float* __restrict__ W,
        const int*   __restrict__ dst,
        const int*   __restrict__ src,
        const float* __restrict__ affine,
        int*            __restrict__ rowptr,
        uint2*          __restrict__ meta,
        unsigned short* __restrict__ Z1b,
        unsigned short* __restrict__ Y) {
    __shared__ short8 Bls[4096];   // 64 KB: both halves of W, bf16

    int tid = threadIdx.x;
    int bid = blockIdx.x;

    if (bid >= NB_M) {
        // ---- prep path: rowptr + meta (edge-parallel, streaming) ----
        int t = (bid - NB_M) * 256 + tid;
        if (t < E_EDGES) {
            int d1 = dst[t];
            int d0 = (t == 0) ? -1 : dst[t - 1];
            for (int n = d0 + 1; n <= d1; ++n) rowptr[n] = t;
            if (t == E_EDGES - 1)
                for (int n = d1 + 1; n <= N_NODES; ++n) rowptr[n] = E_EDGES;
            uint2 m;
            m.x = (unsigned)src[t];
            m.y = __float_as_uint(affine[t]);
            meta[t] = m;
        }
        return;
    }

    // ---- gemm path ----
    // Convert W directly into LDS. Slot s = h*2048 + c*128 + n holds
    // W[h*128+c*8+j][n], j=0..7. Reads coalesced across n (lane dim).
    #pragma unroll
    for (int i = 0; i < 16; ++i) {
        int s = tid + i * 256;
        int n = s & 127;
        int c = (s >> 7) & 15;
        int h = s >> 11;
        int krow = h * 128 + c * 8;
        short8 v;
        #pragma unroll
        for (int j = 0; j < 8; ++j)
            v[j] = (short)f2bf(W[(size_t)(krow + j) * D + n]);
        Bls[s] = v;
    }

    int wave = tid >> 6;
    int lane = tid & 63;
    int m = lane & 31;
    int g = lane >> 5;
    int row0   = bid * 128 + wave * 32;
    int row_a  = row0 + m;
    int rclamp = row_a < N_NODES ? row_a : 0;

    short8 fa[8];
    const float* ap = feat + (size_t)rclamp * D + g * 8;
    #pragma unroll
    for (int ks = 0; ks < 8; ++ks) {
        float4 u = *(const float4*)(ap + ks * 16);
        float4 v = *(const float4*)(ap + ks * 16 + 4);
        short8 a;
        a[0] = (short)f2bf(u.x); a[1] = (short)f2bf(u.y);
        a[2] = (short)f2bf(u.z); a[3] = (short)f2bf(u.w);
        a[4] = (short)f2bf(v.x); a[5] = (short)f2bf(v.y);
        a[6] = (short)f2bf(v.z); a[7] = (short)f2bf(v.w);
        fa[ks] = a;
    }
    __syncthreads();

    #pragma unroll
    for (int h = 0; h < 2; ++h) {
        unsigned short* dstbuf = h ? Y : Z1b;
        #pragma unroll
        for (int t4 = 0; t4 < 4; ++t4) {
            int n = t4 * 32 + m;
            floatx16 acc = {0,0,0,0, 0,0,0,0, 0,0,0,0, 0,0,0,0};
            #pragma unroll
            for (int ks = 0; ks < 8; ++ks) {
                short8 bb = Bls[h * 2048 + (ks * 2 + g) * 128 + n];
                acc = __builtin_amdgcn_mfma_f32_32x32x16_bf16(fa[ks], bb, acc, 0, 0, 0);
            }
            // D layout: col = lane&31, row = (reg&3) + 8*(reg>>2) + 4*g
            #pragma unroll
            for (int r = 0; r < 16; ++r) {
                int row = row0 + (r & 3) + 8 * (r >> 2) + 4 * g;
                if (row < N_NODES) dstbuf[(size_t)row * D + n] = f2bf(acc[r]);
            }
        }
    }
}

// ---------------------------------------------------------------------------
// Kernel 2: out[n,:] = bf2f(Z1b[n,:]) + bias + sum_e affine[e] * Y[src[e],:]
// One wave per node; quarter g owns edge slot, lane owns 8 features (uint4).
// 16 edges in flight per round, CLAMPED always-issued loads (R4 form —
// idle slots all hit the same meta[lo] row -> coalesced L1 hit, ~free;
// predicating them (R5) cost +5us in exec-mask overhead / lost pipelining).
// ---------------------------------------------------------------------------
__global__ __launch_bounds__(256) void agg_add(const unsigned short* __restrict__ Y,
                                               const unsigned short* __restrict__ Z1b,
                                               const uint2* __restrict__ meta,
                                               const int* __restrict__ rowptr,
                                               const float* __restrict__ bias,
                                               float* __restrict__ out) {
    int wave = threadIdx.x >> 6;
    int lane = threadIdx.x & 63;
    int n = blockIdx.x * 4 + wave;
    if (n >= N_NODES) return;
    int lo = rowptr[n], hi = rowptr[n + 1];
    int g  = lane >> 4;
    int jj = (lane & 15) << 3;
    const unsigned short* Yj = Y + jj;

    // Epilogue operands issued early — overlap with the gather chain below.
    uint4  z  = *(const uint4*)(Z1b + (size_t)n * D + jj);
    float4 b0 = *(const float4*)(bias + jj);
    float4 b1 = *(const float4*)(bias + jj + 4);

    float acc[8] = {0,0,0,0,0,0,0,0};

    for (int e0 = lo; e0 < hi; e0 += 16) {
        uint2 md[4];
        #pragma unroll
        for (int u = 0; u < 4; ++u) {
            int i = e0 + u * 4 + g;
            md[u] = meta[i < hi ? i : lo];
        }
        float w[4];
        uint4 p[4];
        #pragma unroll
        for (int u = 0; u < 4; ++u) {
            int i = e0 + u * 4 + g;
            w[u] = (i < hi) ? __uint_as_float(md[u].y) : 0.f;
            p[u] = *(const uint4*)(Yj + (size_t)md[u].x * D);
        }
        #pragma unroll
        for (int u = 0; u < 4; ++u) {
            acc[0] += bflo(p[u].x) * w[u];  acc[1] += bfhi(p[u].x) * w[u];
            acc[2] += bflo(p[u].y) * w[u];  acc[3] += bfhi(p[u].y) * w[u];
            acc[4] += bflo(p[u].z) * w[u];  acc[5] += bfhi(p[u].z) * w[u];
            acc[6] += bflo(p[u].w) * w[u];  acc[7] += bfhi(p[u].w) * w[u];
        }
    }

    #pragma unroll
    for (int r = 0; r < 8; ++r) {
        acc[r] += __shfl_xor(acc[r], 16);
        acc[r] += __shfl_xor(acc[r], 32);
    }

    if (g == 0) {
        float* op = out + (size_t)n * D + jj;
        float4 o0, o1;
        o0.x = bflo(z.x) + b0.x + acc[0];  o0.y = bfhi(z.x) + b0.y + acc[1];
        o0.z = bflo(z.y) + b0.z + acc[2];  o0.w = bfhi(z.y) + b0.w + acc[3];
        o1.x = bflo(z.z) + b1.x + acc[4];  o1.y = bfhi(z.z) + b1.y + acc[5];
        o1.z = bflo(z.w) + b1.z + acc[6];  o1.w = bfhi(z.w) + b1.w + acc[7];
        *(float4*)op       = o0;
        *(float4*)(op + 4) = o1;
    }
}

// ---------------------------------------------------------------------------
extern "C" void kernel_launch(void* const* d_in, const int* in_sizes, int n_in,
                              void* d_out, int out_size, void* d_ws, size_t ws_size,
                              hipStream_t stream) {
    const float* feat   = (const float*)d_in[0];
    const float* affine = (const float*)d_in[1];
    const int*   src    = (const int*)  d_in[2];
    const int*   dst    = (const int*)  d_in[3];
    const float* W      = (const float*)d_in[4];
    const float* bias   = (const float*)d_in[5];
    float*       out    = (float*)d_out;

    // ws: rowptr @64K; meta 5MB @266240; Y 12.8MB @5267456; Z1b @18067456.
    int*            rowptr = (int*)((char*)d_ws + 65536);
    uint2*          meta   = (uint2*)((char*)d_ws + 266240);
    unsigned short* Y      = (unsigned short*)((char*)d_ws + 5267456);
    unsigned short* Z1b    = (unsigned short*)((char*)d_ws + 18067456);

    fused_prep_gemm<<<NB_M + PREP_BLOCKS, 256, 0, stream>>>(
        feat, W, dst, src, affine, rowptr, meta, Z1b, Y);
    agg_add<<<(N_NODES + 3) / 4, 256, 0, stream>>>(Y, Z1b, meta, rowptr, bias, out);
}